// Round 4
// baseline (91.150 us; speedup 1.0000x reference)
//
#include <hip/hip_runtime.h>
#include <hip/hip_bf16.h>

typedef float f32x4 __attribute__((ext_vector_type(4)));

// Fused: each block builds the 3x1024 CRF LUT in LDS, then streams pixels,
// 8 floats (2x float4) per thread per iteration for ILP.
// lut layout: (K,3) interleaved -> lut[k*3 + c]; stride-3 over lanes is
// conflict-free (gcd(3,32)=1). 12 KB LDS -> 8 blocks/CU.
__global__ __launch_bounds__(256) void emor_fused(
        const float* __restrict__ hdr,
        const float* __restrict__ expo,
        const float* __restrict__ f0,
        const float* __restrict__ basis,
        const float* __restrict__ weight,
        float* __restrict__ out,
        int n_flat) {
    __shared__ float lut[3072];

    // --- LUT build: 256 threads x 4 k-values (coalesced over basis rows) ---
    float w[3][11];
#pragma unroll
    for (int c = 0; c < 3; ++c)
#pragma unroll
        for (int d = 0; d < 11; ++d)
            w[c][d] = weight[c * 11 + d];

#pragma unroll
    for (int j = 0; j < 4; ++j) {
        int k = threadIdx.x + 256 * j;
        float f = f0[k];
        float a0 = f, a1 = f, a2 = f;
#pragma unroll
        for (int d = 0; d < 11; ++d) {
            float b = basis[d * 1024 + k];
            a0 = fmaf(w[0][d], b, a0);
            a1 = fmaf(w[1][d], b, a1);
            a2 = fmaf(w[2][d], b, a2);
        }
        lut[k * 3 + 0] = a0;
        lut[k * 3 + 1] = a1;
        lut[k * 3 + 2] = a2;
    }
    __syncthreads();

    const float e = expo[0];
    const int tid    = blockIdx.x * blockDim.x + threadIdx.x;
    const int stride = gridDim.x * blockDim.x * 8;   // grid%3==0 -> stride%3==0

    const int i0 = tid * 8;
    // channel of element (i0+k) is invariant across iterations
    int c[8];
    c[0] = i0 % 3;
#pragma unroll
    for (int k = 1; k < 8; ++k) { c[k] = c[k-1] + 1; if (c[k] == 3) c[k] = 0; }

    for (int i = i0; i < n_flat; i += stride) {
        f32x4 h0 = __builtin_nontemporal_load(
                       reinterpret_cast<const f32x4*>(hdr + i));
        f32x4 h1 = __builtin_nontemporal_load(
                       reinterpret_cast<const f32x4*>(hdr + i + 4));
        float hv[8] = {h0.x, h0.y, h0.z, h0.w, h1.x, h1.y, h1.z, h1.w};
        float rv[8];
#pragma unroll
        for (int k = 0; k < 8; ++k) {
            float u  = fminf(fmaxf(hv[k] * e, 0.0f), 1.0f);  // v_med3 clamp
            float p  = u * 1023.0f;
            float fi = fminf(floorf(p), 1022.0f);
            int   idx = (int)fi;
            float v0 = lut[idx * 3 + c[k]];
            float v1 = lut[idx * 3 + c[k] + 3];
            rv[k] = fmaf(p - fi, v1 - v0, v0);
        }
        f32x4 r0 = {rv[0], rv[1], rv[2], rv[3]};
        f32x4 r1 = {rv[4], rv[5], rv[6], rv[7]};
        __builtin_nontemporal_store(r0, reinterpret_cast<f32x4*>(out + i));
        __builtin_nontemporal_store(r1, reinterpret_cast<f32x4*>(out + i + 4));
    }
}

extern "C" void kernel_launch(void* const* d_in, const int* in_sizes, int n_in,
                              void* d_out, int out_size, void* d_ws, size_t ws_size,
                              hipStream_t stream) {
    const float* hdr    = (const float*)d_in[0];   // (N_PIXELS, 3)
    const float* expo   = (const float*)d_in[1];   // (1,)
    const float* f0     = (const float*)d_in[2];   // (1, 1024)
    const float* basis  = (const float*)d_in[3];   // (11, 1024)
    const float* weight = (const float*)d_in[4];   // (3, 11)
    float* out = (float*)d_out;                    // (N_PIXELS, 3)

    int n_flat = out_size;                         // 50331648, divisible by 8
    int block = 256;
    int grid  = 2046;  // divisible by 3 -> per-thread channels loop-invariant
    emor_fused<<<grid, block, 0, stream>>>(hdr, expo, f0, basis, weight, out, n_flat);
}

// Round 5
// 81.775 us; speedup vs baseline: 1.1147x; 1.1147x over previous
//
#include <hip/hip_runtime.h>
#include <hip/hip_bf16.h>

typedef float f32x4 __attribute__((ext_vector_type(4)));

// Fused: each block builds the 3x1024 CRF LUT (channel-major) in LDS, then
// streams pixels, one float4 per thread per iteration (perfectly coalesced:
// 64 lanes x 16B = 1KB contiguous per load instruction).
// Channel-major LUT -> v0/v1 adjacent -> single ds_read2_b32 per element.
// Grid 1536 divides the work exactly: 1536*256*4*32 == 50331648.
__global__ __launch_bounds__(256) void emor_fused(
        const float* __restrict__ hdr,
        const float* __restrict__ expo,
        const float* __restrict__ f0,
        const float* __restrict__ basis,
        const float* __restrict__ weight,
        float* __restrict__ out,
        int n_flat) {
    __shared__ float lut[3 * 1024];   // lut[c*1024 + k] = crf[c][k]

    // --- LUT build: 256 threads x 4 k-values (coalesced) ---
    float w[3][11];
#pragma unroll
    for (int c = 0; c < 3; ++c)
#pragma unroll
        for (int d = 0; d < 11; ++d)
            w[c][d] = weight[c * 11 + d];

#pragma unroll
    for (int j = 0; j < 4; ++j) {
        int k = threadIdx.x + 256 * j;
        float f = f0[k];
        float a0 = f, a1 = f, a2 = f;
#pragma unroll
        for (int d = 0; d < 11; ++d) {
            float b = basis[d * 1024 + k];
            a0 = fmaf(w[0][d], b, a0);
            a1 = fmaf(w[1][d], b, a1);
            a2 = fmaf(w[2][d], b, a2);
        }
        lut[k]        = a0;   // stride-1 writes: conflict-free
        lut[k + 1024] = a1;
        lut[k + 2048] = a2;
    }
    __syncthreads();

    const float e = expo[0];
    const int tid    = blockIdx.x * blockDim.x + threadIdx.x;
    const int stride = gridDim.x * blockDim.x * 4;   // %3 == 0 (grid%3==0)

    const int i0 = tid * 4;
    // channel base offsets (c<<10), loop-invariant since stride%3==0
    int cb[4];
    cb[0] = (i0 % 3) << 10;
#pragma unroll
    for (int k = 1; k < 4; ++k) {
        cb[k] = cb[k - 1] + 1024;
        if (cb[k] == 3072) cb[k] = 0;
    }

    for (int i = i0; i < n_flat; i += stride) {
        f32x4 h = __builtin_nontemporal_load(
                      reinterpret_cast<const f32x4*>(hdr + i));
        float hv[4] = {h.x, h.y, h.z, h.w};
        f32x4 r;
        float rv[4];
#pragma unroll
        for (int k = 0; k < 4; ++k) {
            float u  = fminf(fmaxf(hv[k] * e, 0.0f), 1.0f);  // v_med3 clamp
            float p  = u * 1023.0f;
            float fi = fminf(floorf(p), 1022.0f);
            int   a  = cb[k] + (int)fi;
            float v0 = lut[a];        // adjacent pair -> ds_read2_b32
            float v1 = lut[a + 1];
            rv[k] = fmaf(p - fi, v1 - v0, v0);
        }
        r.x = rv[0]; r.y = rv[1]; r.z = rv[2]; r.w = rv[3];
        __builtin_nontemporal_store(r, reinterpret_cast<f32x4*>(out + i));
    }
}

extern "C" void kernel_launch(void* const* d_in, const int* in_sizes, int n_in,
                              void* d_out, int out_size, void* d_ws, size_t ws_size,
                              hipStream_t stream) {
    const float* hdr    = (const float*)d_in[0];   // (N_PIXELS, 3)
    const float* expo   = (const float*)d_in[1];   // (1,)
    const float* f0     = (const float*)d_in[2];   // (1, 1024)
    const float* basis  = (const float*)d_in[3];   // (11, 1024)
    const float* weight = (const float*)d_in[4];   // (3, 11)
    float* out = (float*)d_out;                    // (N_PIXELS, 3)

    int n_flat = out_size;  // 50331648 = 1536*256*4*32 -> perfectly balanced
    int block = 256;
    int grid  = 1536;       // divisible by 3; 6 blocks/CU, fully resident
    emor_fused<<<grid, block, 0, stream>>>(hdr, expo, f0, basis, weight, out, n_flat);
}

// Round 6
// 79.415 us; speedup vs baseline: 1.1478x; 1.0297x over previous
//
#include <hip/hip_runtime.h>
#include <hip/hip_bf16.h>

typedef float f32x4 __attribute__((ext_vector_type(4)));

// Fused: each block builds the 3x1024 CRF LUT (channel-major) in LDS, then
// streams pixels, one float4 per thread per iteration (64 lanes x 16B = 1KB
// contiguous per load instruction).
// grid=2048: 8 blocks/CU (32 waves/CU, max occupancy) AND divides the work
// exactly: 2048*256*4*24 == 50331648 -> every thread does 24 iterations.
// stride % 3 == 2 -> channel bases rotate by +2048 (mod 3072) per iteration,
// maintained in registers (2 VALU ops/slot, off the memory critical path).
__global__ __launch_bounds__(256) void emor_fused(
        const float* __restrict__ hdr,
        const float* __restrict__ expo,
        const float* __restrict__ f0,
        const float* __restrict__ basis,
        const float* __restrict__ weight,
        float* __restrict__ out,
        int n_flat) {
    __shared__ float lut[3 * 1024];   // lut[c*1024 + k] = crf[c][k]

    // --- LUT build: 256 threads x 4 k-values (coalesced) ---
    float w[3][11];
#pragma unroll
    for (int c = 0; c < 3; ++c)
#pragma unroll
        for (int d = 0; d < 11; ++d)
            w[c][d] = weight[c * 11 + d];

#pragma unroll
    for (int j = 0; j < 4; ++j) {
        int k = threadIdx.x + 256 * j;
        float f = f0[k];
        float a0 = f, a1 = f, a2 = f;
#pragma unroll
        for (int d = 0; d < 11; ++d) {
            float b = basis[d * 1024 + k];
            a0 = fmaf(w[0][d], b, a0);
            a1 = fmaf(w[1][d], b, a1);
            a2 = fmaf(w[2][d], b, a2);
        }
        lut[k]        = a0;   // stride-1 writes: conflict-free
        lut[k + 1024] = a1;
        lut[k + 2048] = a2;
    }
    __syncthreads();

    const float e = expo[0];
    const int tid    = blockIdx.x * blockDim.x + threadIdx.x;
    const int stride = gridDim.x * blockDim.x * 4;

    const int i0 = tid * 4;
    // channel base offset (channel << 10) for each of the 4 slots
    int cb[4];
    cb[0] = (i0 % 3) << 10;
#pragma unroll
    for (int k = 1; k < 4; ++k) {
        cb[k] = cb[k - 1] + 1024;
        if (cb[k] == 3072) cb[k] = 0;
    }
    // per-iteration channel rotation: +stride elements ≡ +(stride%3) channels
    const int rot = (stride % 3) << 10;   // 0, 1024 or 2048

    for (int i = i0; i < n_flat; i += stride) {
        f32x4 h = __builtin_nontemporal_load(
                      reinterpret_cast<const f32x4*>(hdr + i));
        float hv[4] = {h.x, h.y, h.z, h.w};
        f32x4 r;
        float rv[4];
#pragma unroll
        for (int k = 0; k < 4; ++k) {
            float u  = fminf(fmaxf(hv[k] * e, 0.0f), 1.0f);  // v_med3 clamp
            float p  = u * 1023.0f;
            float fi = fminf(floorf(p), 1022.0f);
            int   a  = cb[k] + (int)fi;
            float v0 = lut[a];        // adjacent pair -> ds_read2_b32
            float v1 = lut[a + 1];
            rv[k] = fmaf(p - fi, v1 - v0, v0);
            // rotate channel base for next iteration (cheap, independent)
            cb[k] += rot;
            if (cb[k] >= 3072) cb[k] -= 3072;
        }
        r.x = rv[0]; r.y = rv[1]; r.z = rv[2]; r.w = rv[3];
        __builtin_nontemporal_store(r, reinterpret_cast<f32x4*>(out + i));
    }
}

extern "C" void kernel_launch(void* const* d_in, const int* in_sizes, int n_in,
                              void* d_out, int out_size, void* d_ws, size_t ws_size,
                              hipStream_t stream) {
    const float* hdr    = (const float*)d_in[0];   // (N_PIXELS, 3)
    const float* expo   = (const float*)d_in[1];   // (1,)
    const float* f0     = (const float*)d_in[2];   // (1, 1024)
    const float* basis  = (const float*)d_in[3];   // (11, 1024)
    const float* weight = (const float*)d_in[4];   // (3, 11)
    float* out = (float*)d_out;                    // (N_PIXELS, 3)

    int n_flat = out_size;  // 50331648 = 2048*256*4*24 -> zero tail
    int block = 256;
    int grid  = 2048;       // 8 blocks/CU -> 32 waves/CU (max residency)
    emor_fused<<<grid, block, 0, stream>>>(hdr, expo, f0, basis, weight, out, n_flat);
}

// Round 7
// 77.776 us; speedup vs baseline: 1.1720x; 1.0211x over previous
//
#include <hip/hip_runtime.h>
#include <hip/hip_bf16.h>

typedef float f32x4 __attribute__((ext_vector_type(4)));

// Fused LUT-build + apply. Per thread, TWO independent float4 chains per
// loop iteration at i and i+S (S = whole-grid stride): each load instruction
// stays perfectly coalesced (64 lanes x 16B contiguous) while doubling
// in-flight VMEM per thread (round-4 lesson: never widen the per-thread
// contiguous span; unroll ACROSS grid-stride iterations instead).
// grid=2048: 8 blocks/CU, and 2048*256*4*24 == n exactly -> 12 double-iters,
// zero tail. 2S % 3 == 1 -> channel bases rotate +1024 (mod 3072) per iter.
__global__ __launch_bounds__(256) void emor_fused(
        const float* __restrict__ hdr,
        const float* __restrict__ expo,
        const float* __restrict__ f0,
        const float* __restrict__ basis,
        const float* __restrict__ weight,
        float* __restrict__ out,
        int n_flat) {
    __shared__ float lut[3 * 1024];   // lut[c*1024 + k] = crf[c][k]

    // --- LUT build: 256 threads x 4 k-values (coalesced) ---
    float w[3][11];
#pragma unroll
    for (int c = 0; c < 3; ++c)
#pragma unroll
        for (int d = 0; d < 11; ++d)
            w[c][d] = weight[c * 11 + d];

#pragma unroll
    for (int j = 0; j < 4; ++j) {
        int k = threadIdx.x + 256 * j;
        float f = f0[k];
        float a0 = f, a1 = f, a2 = f;
#pragma unroll
        for (int d = 0; d < 11; ++d) {
            float b = basis[d * 1024 + k];
            a0 = fmaf(w[0][d], b, a0);
            a1 = fmaf(w[1][d], b, a1);
            a2 = fmaf(w[2][d], b, a2);
        }
        lut[k]        = a0;
        lut[k + 1024] = a1;
        lut[k + 2048] = a2;
    }
    __syncthreads();

    const float e = expo[0];
    const int tid = blockIdx.x * blockDim.x + threadIdx.x;
    const int S   = gridDim.x * blockDim.x * 4;      // 2097152, S%3==2

    const int i0 = tid * 4;
    int cb[4];                                        // channel<<10 per slot
    cb[0] = (i0 % 3) << 10;
#pragma unroll
    for (int k = 1; k < 4; ++k) {
        cb[k] = cb[k - 1] + 1024;
        if (cb[k] == 3072) cb[k] = 0;
    }

    for (int i = i0; i < n_flat; i += 2 * S) {
        // both independent loads issued up front
        f32x4 hA = __builtin_nontemporal_load(
                       reinterpret_cast<const f32x4*>(hdr + i));
        f32x4 hB = __builtin_nontemporal_load(
                       reinterpret_cast<const f32x4*>(hdr + i + S));
        float hvA[4] = {hA.x, hA.y, hA.z, hA.w};
        float hvB[4] = {hB.x, hB.y, hB.z, hB.w};
        float rvA[4], rvB[4];
#pragma unroll
        for (int k = 0; k < 4; ++k) {
            // chain A: channel base cb[k]
            float uA  = fminf(fmaxf(hvA[k] * e, 0.0f), 1.0f);
            float pA  = uA * 1023.0f;
            float fiA = fminf(floorf(pA), 1022.0f);
            int   aA  = cb[k] + (int)fiA;
            float v0A = lut[aA];
            float v1A = lut[aA + 1];
            rvA[k] = fmaf(pA - fiA, v1A - v0A, v0A);
            // chain B: +S elements -> channel +2 (S%3==2) -> base +2048
            int bB = cb[k] + 2048; if (bB >= 3072) bB -= 3072;
            float uB  = fminf(fmaxf(hvB[k] * e, 0.0f), 1.0f);
            float pB  = uB * 1023.0f;
            float fiB = fminf(floorf(pB), 1022.0f);
            int   aB  = bB + (int)fiB;
            float v0B = lut[aB];
            float v1B = lut[aB + 1];
            rvB[k] = fmaf(pB - fiB, v1B - v0B, v0B);
            // advance channel for next double-iter: +2S ≡ +1 (mod 3)
            cb[k] += 1024; if (cb[k] == 3072) cb[k] = 0;
        }
        f32x4 rA = {rvA[0], rvA[1], rvA[2], rvA[3]};
        f32x4 rB = {rvB[0], rvB[1], rvB[2], rvB[3]};
        __builtin_nontemporal_store(rA, reinterpret_cast<f32x4*>(out + i));
        __builtin_nontemporal_store(rB, reinterpret_cast<f32x4*>(out + i + S));
    }
}

extern "C" void kernel_launch(void* const* d_in, const int* in_sizes, int n_in,
                              void* d_out, int out_size, void* d_ws, size_t ws_size,
                              hipStream_t stream) {
    const float* hdr    = (const float*)d_in[0];   // (N_PIXELS, 3)
    const float* expo   = (const float*)d_in[1];   // (1,)
    const float* f0     = (const float*)d_in[2];   // (1, 1024)
    const float* basis  = (const float*)d_in[3];   // (11, 1024)
    const float* weight = (const float*)d_in[4];   // (3, 11)
    float* out = (float*)d_out;                    // (N_PIXELS, 3)

    int n_flat = out_size;  // 50331648 = 2048*256*4*24 -> 12 double-iters
    int block = 256;
    int grid  = 2048;       // 8 blocks/CU -> 32 waves/CU
    emor_fused<<<grid, block, 0, stream>>>(hdr, expo, f0, basis, weight, out, n_flat);
}